// Round 3
// baseline (5323.897 us; speedup 1.0000x reference)
//
#include <hip/hip_runtime.h>
#include <hip/hip_bf16.h>

#define NN 6144
#define DD 64
#define NL 3
#define KK 24
#define RT 32   // rows per block (adj kernel)
#define CT 64   // cols per tile
#define NT (NN / CT)

// Bit-level emulation of XLA CPU f32 tanh, FMA variant (llvm_ir::EmitFastTanh
// with_fma=true / Eigen ptanh AVX2+): clamp to +-7.99881172180175781, Horner
// via fused fma, |x|<4e-4 -> x. Verified bit-exact vs reference (round 2,
// absmax 0.0).
__device__ __forceinline__ float tanh_xla(float x) {
  const float kClamp = 7.99881172180175781f;
  float xc = fminf(fmaxf(x, -kClamp), kClamp);
  float x2 = xc * xc;
  float p = -2.76076847742355e-16f;
  p = fmaf(p, x2, 2.00018790482477e-13f);
  p = fmaf(p, x2, -8.60467152213735e-11f);
  p = fmaf(p, x2, 5.12229709037114e-08f);
  p = fmaf(p, x2, 1.48572235717979e-05f);
  p = fmaf(p, x2, 6.37261928875436e-04f);
  p = fmaf(p, x2, 4.89352455891786e-03f);
  p = xc * p;
  float q = 1.19825839466702e-06f;
  q = fmaf(q, x2, 1.18534705686654e-04f);
  q = fmaf(q, x2, 2.26843463243900e-03f);
  q = fmaf(q, x2, 4.89352518554385e-03f);
  float r = p / q;
  return (fabsf(x) < 0.0004f) ? x : r;
}

#define KCLAMP 7.99881172180175781f

// Kernel A: 3-layer tanh MLP chains. Thread = one row. Sequential-k fmaf
// chains (bit-matches Eigen). Emits BOTH row-major v (layer chaining, R-tile
// staging) and k-major vT (adj kernel B-operand, coalesced: consecutive
// threads = consecutive rows).
__global__ __launch_bounds__(256) void mlp_kernel(
    const int* __restrict__ idx, const float* __restrict__ scale_set,
    const float* __restrict__ emb1, const float* __restrict__ emb2,
    const float* __restrict__ W1, const float* __restrict__ b1,
    const float* __restrict__ W2, const float* __restrict__ b2,
    float* __restrict__ v1s, float* __restrict__ v2s,
    float* __restrict__ vt1, float* __restrict__ vt2) {
  __shared__ float Wsh1[DD * DD];
  __shared__ float Wsh2[DD * DD];
  __shared__ float bsh1[DD];
  __shared__ float bsh2[DD];
  const int t = threadIdx.x;
  const int row = blockIdx.x * 256 + t;

  float u1[DD], u2[DD];

  for (int l = 0; l < NL; ++l) {
    __syncthreads();
    for (int i = t; i < (DD * DD) / 4; i += 256) {
      ((float4*)Wsh1)[i] = ((const float4*)(W1 + l * DD * DD))[i];
      ((float4*)Wsh2)[i] = ((const float4*)(W2 + l * DD * DD))[i];
    }
    if (t < DD) { bsh1[t] = b1[l * DD + t]; bsh2[t] = b2[l * DD + t]; }
    __syncthreads();

    const float s = scale_set[l];
    const float* src1;
    const float* src2;
    if (l == 0) {
      int g = idx[row];
      src1 = emb1 + (size_t)g * DD;
      src2 = emb2 + (size_t)g * DD;
    } else {
      src1 = v1s + ((size_t)(l - 1) * NN + row) * DD;
      src2 = v2s + ((size_t)(l - 1) * NN + row) * DD;
    }
#pragma unroll
    for (int k = 0; k < DD; ++k) {
      u1[k] = src1[k] * s;
      u2[k] = src2[k] * s;
    }
    float* o1 = v1s + ((size_t)l * NN + row) * DD;
    float* o2 = v2s + ((size_t)l * NN + row) * DD;
    float* ot1 = vt1 + (size_t)l * DD * NN + row;
    float* ot2 = vt2 + (size_t)l * DD * NN + row;
    for (int j = 0; j < DD; ++j) {
      float a1 = 0.0f, a2 = 0.0f;
#pragma unroll
      for (int k = 0; k < DD; ++k) {
        a1 = fmaf(u1[k], Wsh1[j * DD + k], a1);
        a2 = fmaf(u2[k], Wsh2[j * DD + k], a2);
      }
      float t1 = tanh_xla(3.0f * (a1 + bsh1[j]));
      float t2 = tanh_xla(3.0f * (a2 + bsh2[j]));
      o1[j] = t1;
      o2[j] = t2;
      ot1[(size_t)j * NN] = t1;
      ot2[(size_t)j * NN] = t2;
    }
  }
}

// Kernel B: per (layer, 32-row tile): zero-fill output slab; per 64-col tile
// compute exact a = v1.v2c - v2.v1c (B-operand streamed from L2-resident
// k-major vT, no LDS staging); scan with sound a-domain prefilter + plateau
// fast-path; stable top-24 (value desc, index asc); scatter.
__global__ __launch_bounds__(128, 3) void adj_kernel(
    const float* __restrict__ v1s, const float* __restrict__ v2s,
    const float* __restrict__ vt1, const float* __restrict__ vt2,
    float* __restrict__ out) {
  __shared__ float R1t[DD][RT];      // [k][row]
  __shared__ float R2t[DD][RT];
  __shared__ float A[RT][CT + 1];    // a-tile, padded (bank-conflict-free scan)
  __shared__ float kv[KK][RT];       // topk values, slot 0 = weakest
  __shared__ int   ki[KK][RT];
  // LDS total: 16K + 8.3K + 6K = 30.6 KiB -> 5 blocks/CU

  const int l = blockIdx.y;
  const int r0 = blockIdx.x * RT;
  const int t = threadIdx.x;
  const float* v1 = v1s + (size_t)l * NN * DD;
  const float* v2 = v2s + (size_t)l * NN * DD;
  const float* w1 = vt1 + (size_t)l * DD * NN;   // [k][col]
  const float* w2 = vt2 + (size_t)l * DD * NN;
  float* o = out + (size_t)l * NN * NN;

  // tanh_xla is constant for any x >= kClamp (clamp): the exact plateau value.
  const float Rclamp = tanh_xla(8.0f);

  // Zero-fill this block's 32-row output slab.
  {
    float4 z = make_float4(0.f, 0.f, 0.f, 0.f);
    float4* dst = (float4*)(o + (size_t)r0 * NN);
    for (int i = t; i < RT * NN / 4; i += 128) dst[i] = z;
  }

  // Stage row-side vectors transposed: R1t[k][r] = v1[r0+r][k].
  {
    int r = t >> 2;
    int k0 = (t & 3) * 16;
#pragma unroll
    for (int i = 0; i < 4; ++i) {
      float4 g1 = *(const float4*)(v1 + (size_t)(r0 + r) * DD + k0 + i * 4);
      float4 g2 = *(const float4*)(v2 + (size_t)(r0 + r) * DD + k0 + i * 4);
      int kk = k0 + i * 4;
      R1t[kk + 0][r] = g1.x; R1t[kk + 1][r] = g1.y; R1t[kk + 2][r] = g1.z; R1t[kk + 3][r] = g1.w;
      R2t[kk + 0][r] = g2.x; R2t[kk + 1][r] = g2.y; R2t[kk + 2][r] = g2.z; R2t[kk + 3][r] = g2.w;
    }
  }
  if (t < RT) {
#pragma unroll
    for (int j = 0; j < KK; ++j) { kv[j][t] = 0.0f; ki[j][t] = 0; }
  }
  float kv0 = 0.0f;
  float athr = 0.0f;  // sound reject threshold in x=fl(3a) domain

  const int ty = t >> 4;   // 0..7 -> 4 rows
  const int tx = t & 15;   // 0..15 -> 4 cols

  for (int ct = 0; ct <= NT; ++ct) {
    // Scan previous tile (lane = row). Prefilter: x <= athr => r(x) <= kv0
    // (r(x) <= tanh(x)+1e-6; athr = atanh(kv0-2e-6)-4e-6 with conservative
    // margins). Plateau: x >= kClamp => tanh_xla(x) == Rclamp exactly.
    if (ct > 0 && t < RT) {
      int cb = (ct - 1) * CT;
      for (int c = 0; c < CT; ++c) {
        float x = 3.0f * A[t][c];
        if (x > athr) {
          float tv = (x >= KCLAMP) ? Rclamp : tanh_xla(x);
          if (tv > kv0) {
            int p = 1;
            while (p < KK && kv[p][t] < tv) {
              kv[p - 1][t] = kv[p][t]; ki[p - 1][t] = ki[p][t];
              ++p;
            }
            kv[p - 1][t] = tv; ki[p - 1][t] = cb + c;
            kv0 = kv[0][t];
            float y = kv0 - 2e-6f;
            athr = (y > 0.0f) ? (0.5f * logf((1.0f + y) / (1.0f - y)) - 4e-6f)
                              : 0.0f;
          }
        }
      }
    }
    __syncthreads();
    // Compute tile ct: 4x4 register tile; A-operand from LDS (R tiles),
    // B-operand float4 direct from L2-resident vT. Sequential-k fmaf chains.
    if (ct < NT) {
      const int c0 = ct * CT + 4 * tx;
      float acc1[4][4] = {{0.f}}, acc2[4][4] = {{0.f}};
      const float* p1 = w1 + c0;
      const float* p2 = w2 + c0;
#pragma unroll 8
      for (int k = 0; k < DD; ++k) {
        float4 rv1 = *(const float4*)&R1t[k][4 * ty];
        float4 rv2 = *(const float4*)&R2t[k][4 * ty];
        float4 cv1 = *(const float4*)(p1 + (size_t)k * NN);
        float4 cv2 = *(const float4*)(p2 + (size_t)k * NN);
        const float* r1 = (const float*)&rv1;
        const float* r2 = (const float*)&rv2;
        const float* c1 = (const float*)&cv1;
        const float* c2 = (const float*)&cv2;
#pragma unroll
        for (int i = 0; i < 4; ++i)
#pragma unroll
          for (int j = 0; j < 4; ++j) {
            acc1[i][j] = fmaf(r1[i], c2[j], acc1[i][j]);  // v1_r . v2_c
            acc2[i][j] = fmaf(r2[i], c1[j], acc2[i][j]);  // v2_r . v1_c
          }
      }
#pragma unroll
      for (int i = 0; i < 4; ++i)
#pragma unroll
        for (int j = 0; j < 4; ++j)
          A[4 * ty + i][4 * tx + j] = acc1[i][j] - acc2[i][j];
    }
    __syncthreads();
  }

  // Scatter top-24 nonzeros into the zeroed slab.
  if (t < RT) {
    float* orow = o + (size_t)(r0 + t) * NN;
#pragma unroll
    for (int j = 0; j < KK; ++j) {
      float v = kv[j][t];
      if (v > 0.0f) orow[ki[j][t]] = v;
    }
  }
}

extern "C" void kernel_launch(void* const* d_in, const int* in_sizes, int n_in,
                              void* d_out, int out_size, void* d_ws, size_t ws_size,
                              hipStream_t stream) {
  const int*   idx       = (const int*)d_in[0];
  const float* scale_set = (const float*)d_in[2];
  const float* emb1      = (const float*)d_in[3];
  const float* emb2      = (const float*)d_in[4];
  const float* W1        = (const float*)d_in[5];
  const float* b1        = (const float*)d_in[6];
  const float* W2        = (const float*)d_in[7];
  const float* b2        = (const float*)d_in[8];
  float* out = (float*)d_out;

  const size_t VS = (size_t)NL * NN * DD;
  float* v1s = (float*)d_ws;      // row-major [3][6144][64]
  float* v2s = v1s + VS;
  float* vt1 = v2s + VS;          // k-major [3][64][6144]
  float* vt2 = vt1 + VS;          // total 18.9 MB

  mlp_kernel<<<NN / 256, 256, 0, stream>>>(idx, scale_set, emb1, emb2, W1, b1, W2, b2,
                                           v1s, v2s, vt1, vt2);
  adj_kernel<<<dim3(NN / RT, NL), 128, 0, stream>>>(v1s, v2s, vt1, vt2, out);
}